// Round 11
// baseline (327.250 us; speedup 1.0000x reference)
//
#include <hip/hip_runtime.h>
#include <hip/hip_bf16.h>

#define BB 20
#define SS 500
#define DIMD 300
#define HIDH 600
#define QKD 128

typedef unsigned short u16;
typedef __attribute__((ext_vector_type(8))) __bf16 bf16x8;
typedef __attribute__((ext_vector_type(8))) short short8;
typedef __attribute__((ext_vector_type(4))) float floatx4;

__device__ __forceinline__ u16 f2bu(float f) {
    __hip_bfloat16 h = __float2bfloat16(f);
    return *reinterpret_cast<u16*>(&h);
}
__device__ __forceinline__ float bu2f(u16 u) {
    unsigned v = ((unsigned)u) << 16;
    return __uint_as_float(v);
}

__device__ __forceinline__ floatx4 mfma_bf16(short8 a, short8 b, floatx4 c) {
    return __builtin_amdgcn_mfma_f32_16x16x32_bf16(
        __builtin_bit_cast(bf16x8, a), __builtin_bit_cast(bf16x8, b), c, 0, 0, 0);
}

// async global->LDS, 16B/lane; LDS dest = wave-uniform base + lane*16
__device__ __forceinline__ void glds16(const u16* g, u16* l) {
    __builtin_amdgcn_global_load_lds(
        (__attribute__((address_space(1))) const void*)g,
        (__attribute__((address_space(3))) void*)l, 16, 0, 0);
}

// ---------------- merged prep + LayerNorm/shift ----------------
__global__ __launch_bounds__(256)
void prep_ln_kernel(const float* __restrict__ x, const float* __restrict__ lng,
                    const float* __restrict__ lnb, u16* __restrict__ nxb,
                    const float* __restrict__ Wh, const float* __restrict__ Wqk,
                    const float* __restrict__ Wout, const float* __restrict__ rel_emb,
                    u16* __restrict__ WhT, u16* __restrict__ Wqkb,
                    u16* __restrict__ WoutT, float* __restrict__ bias,
                    int* __restrict__ hist, unsigned* __restrict__ gmaxu) {
    long id = (long)blockIdx.x * 256 + threadIdx.x;
    if (id < 640000) {                        // LayerNorm + shift, one wave per row
        int bs = id >> 6;
        int t = id & 63;
        int s = bs % SS;
        const float* xr = x + (long)bs * DIMD;
        float sum = 0.f, sq = 0.f;
        for (int d = t; d < DIMD; d += 64) { float v = xr[d]; sum += v; sq += v * v; }
        for (int off = 1; off < 64; off <<= 1) {
            sum += __shfl_xor(sum, off);
            sq  += __shfl_xor(sq, off);
        }
        float mean = sum * (1.f / DIMD);
        float var  = sq * (1.f / DIMD) - mean * mean;
        float rstd = rsqrtf(var + 1e-5f);
        for (int d = t; d < DIMD; d += 64) {
            float nv = (xr[d] - mean) * rstd * lng[d] + lnb[d];
            if (d < DIMD / 2) {
                if (s < SS - 1) nxb[(long)(bs + 1) * 320 + d] = f2bu(nv);
            } else {
                nxb[(long)bs * 320 + d] = f2bu(nv);
            }
        }
        if (s == 0)
            for (int d = t; d < DIMD / 2; d += 64) nxb[(long)bs * 320 + d] = 0;
        for (int d = DIMD + t; d < 320; d += 64) nxb[(long)bs * 320 + d] = 0;
        return;
    }
    id -= 640000;
    if (id < 384000) {                        // WhT[n][k], k<320
        int k = id / 1200, n = id - (long)k * 1200;
        WhT[(long)n * 320 + k] = (k < 300) ? f2bu(Wh[(long)k * 1200 + n]) : (u16)0;
        return;
    }
    id -= 384000;
    if (id < 40960) {                         // Wqkb[n][k]
        int k = id / 128, n = id - (long)k * 128;
        Wqkb[(long)n * 320 + k] = (k < 300) ? f2bu(Wqk[(long)k * 128 + n]) : (u16)0;
        return;
    }
    id -= 40960;
    if (id < 182400) {                        // WoutT[n][k], k<608
        int k = id / 300, n = id - (long)k * 300;
        WoutT[(long)n * 608 + k] = (k < 600) ? f2bu(Wout[(long)k * 300 + n]) : (u16)0;
        return;
    }
    id -= 182400;
    if (id < 250000) {                        // T5 bias 500x500
        int i = id / 500, j = id - (long)i * 500;
        int n = i - j;
        int ret = (n < 0) ? 16 : 0;
        int na = n < 0 ? -n : n;
        int bucket;
        if (na < 8) bucket = ret + na;
        else {
            int vil = 8 + (int)(logf((float)na * 0.125f) / logf(16.f) * 8.f);
            vil = vil < 15 ? vil : 15;
            bucket = ret + vil;
        }
        bias[id] = rel_emb[bucket] * 11.313708498984761f;
        return;
    }
    id -= 250000;
    if (id < 5120) { hist[id] = 0; return; }   // 20 batches x 256-int stride
    id -= 5120;
    if (id < 1280) gmaxu[id] = 0u;             // 20 batches x 64-uint stride
}

// ---------------- Epilogues ----------------
struct EpiH {            // gemm1 transposed: m = hidden [0,1200), n = token [0,10000)
    const float* bh; u16* vT; float* gateT;
    __device__ void operator()(float acc, int bz, int m, int n) const {
        if (m >= 1200 || n >= 10000) return;
        float v = acc + bh[m];
        v = v / (1.f + expf(-v));
        int b = n / SS, s = n - b * SS;
        if (m < HIDH) vT[((long)b * 640 + m) * 512 + s] = f2bu(v);
        else gateT[((long)b * HIDH + (m - HIDH)) * SS + s] = v;
    }
};
struct EpiQKRot {        // qk + silu + gamma/beta + rotary (NO early return: shuffles)
    const float* bqk; const float* gamma; const float* beta;
    u16* qb; u16* kb;
    __device__ void operator()(float acc, int bz, int m, int n) const {
        float v = acc + bqk[n];
        v = v / (1.f + expf(-v));
        float qp = v * gamma[n] + beta[n];
        float kp = v * gamma[QKD + n] + beta[QKD + n];
        float qx = __shfl_xor(qp, 1);
        float kx = __shfl_xor(kp, 1);
        float qo = qp, ko = kp;
        if (n < 32) {
            int s = m % SS;
            float inv = expf(-(float)(n & ~1) * (logf(10000.f) / 32.f));
            float ang = (float)s * inv;
            float c, sn;
            sincosf(ang, &sn, &c);
            float qr = (n & 1) ? qx : -qx;
            float kr = (n & 1) ? kx : -kx;
            qo = qp * c + qr * sn;
            ko = kp * c + kr * sn;
        }
        if (m < 10000) {
            qb[(long)m * QKD + n] = f2bu(qo);
            kb[(long)m * QKD + n] = f2bu(ko);
        }
    }
};
struct EpiAttnB {        // scores -> (relu((s+bias)/S))^2 * mask -> bf16 [500][512]
    const float* bias; const float* mask; u16* attnb;
    __device__ void operator()(float acc, int b, int m, int n) const {
        if (m >= SS || n >= 512) return;
        float r = 0.f;
        if (n < SS) {
            float s = (acc + bias[m * SS + n]) * (1.f / (float)SS);
            s = fmaxf(s, 0.f);
            r = s * s * mask[m * SS + n];
        }
        attnb[((long)b * SS + m) * 512 + n] = f2bu(r);
    }
};
struct EpiGateN {        // gated = gm * (attn@v) * gate -> bf16 [10000][608]
    const u16* gateNb; const int* counts; const int* t2v; u16* gated;
    __device__ void operator()(float acc, int b, int m, int n) const {
        if (m >= SS || n >= 608) return;
        float r = 0.f;
        if (n < HIDH) {
            float g = bu2f(gateNb[((long)b * SS + m) * HIDH + n]);
            int c = counts[(b * 100 + m / 5) * 120 + n / 5];
            float bv = (c >= t2v[b]) ? 1.f : 0.25f;
            float p = ((m % 5) == 4 || (n % 5) == 4) ? 0.f : 1.f;
            r = acc * g * bv * p;
        }
        gated[((long)(b * SS + m)) * 608 + n] = f2bu(r);
    }
};
struct EpiOutB {         // out = gated@Wout + bout + x
    const float* bout; const float* x; float* out;
    __device__ void operator()(float acc, int b, int m, int n) const {
        if (m >= 10000 || n >= DIMD) return;
        out[(long)m * DIMD + n] = acc + bout[n] + x[(long)m * DIMD + n];
    }
};

// ---------------- barrier-free bf16 MFMA GEMM, XCD-pinned, 64x64 wave tiles ----------------
// C[M,N] = A[M,Kp] * Bt[N,Kp]^T.  Block 128x128 = 4 waves in 2x2; each wave
// owns a 64x64 tile with its OWN private LDS double-buffer (no __syncthreads
// anywhere -> no compiler vmcnt(0) drain; per-wave s_waitcnt vmcnt(8) keeps
// the prefetch in flight while the current buffer's 8 glds are retired —
// retirement is issue-ordered, m135).  Grid is 1-D with XCD pinning
// (workgroup->XCD is round-robin on linear id): MODE 0 = batch g -> XCD g%8
// (bz=g); MODE 1 = slice N, group g owns n-tiles [g*TX,(g+1)*TX); MODE 2 =
// slice M likewise.  Each XCD's working set then fits its private 4MB L2.
// Early whole-block return is safe (no barriers).  Staging has NO bounds
// checks: overruns read adjacent ws buffers (finite garbage discarded by
// epilogue guards; 0xAA-poison bf16 is ~3e-13, and every K-pad that matters
// is real zeros on at least one operand side).
template<int MODE, class Epi>
__global__ __launch_bounds__(256)
void gemm_nb(const u16* __restrict__ A, const u16* __restrict__ Bt,
             int Kp, int lda, int ldb, long sA, long sB,
             int TX, int TY, int bound, Epi epi) {
    int lin = blockIdx.x;
    int xcd = lin & 7, i = lin >> 3;
    int per = TX * TY;
    int w = i / per;
    int tl = i - w * per;
    int g = xcd + (w << 3);
    int tx = tl % TX, ty = tl / TX;
    int bx, by, bz;
    if (MODE == 0)      { if (g >= bound) return; bx = tx; by = ty; bz = g; }
    else if (MODE == 1) { bx = g * TX + tx; if (bx >= bound) return; by = ty; bz = 0; }
    else                { by = g * TY + ty; if (by >= bound) return; bx = tx; bz = 0; }

    A += (long)bz * sA; Bt += (long)bz * sB;
    int t = threadIdx.x, lane = t & 63, wave = t >> 6;
    int l15 = lane & 15, l4 = lane >> 4;
    int m0 = (by << 7) + ((wave >> 1) << 6);   // wave's 64-row m base
    int n0 = (bx << 7) + ((wave & 1) << 6);    // wave's 64-col n base

    // per-wave private: [buf][row 0..63=A, 64..127=B][32]; unpadded 64B rows
    __shared__ __align__(16) u16 S[4][2][128][32];

    int srow = lane >> 2, scol = (lane & 3) << 3;
    const u16* ag[4];
    const u16* bg[4];
#pragma unroll
    for (int r = 0; r < 4; ++r) {
        ag[r] = A  + (long)(m0 + r * 16 + srow) * lda + scol;
        bg[r] = Bt + (long)(n0 + r * 16 + srow) * ldb + scol;
    }

    floatx4 acc[4][4];
#pragma unroll
    for (int i2 = 0; i2 < 4; ++i2)
#pragma unroll
        for (int j = 0; j < 4; ++j) acc[i2][j] = (floatx4){0.f, 0.f, 0.f, 0.f};

    // prologue: stage k=0 into buf 0 (8 outstanding)
#pragma unroll
    for (int r = 0; r < 4; ++r) {
        glds16(ag[r], &S[wave][0][r * 16][0]);
        glds16(bg[r], &S[wave][0][64 + r * 16][0]);
    }

    for (int k0 = 0; k0 < Kp; k0 += 32) {
        int buf = (k0 >> 5) & 1;
        int kn = k0 + 32;
        if (kn < Kp) {                       // prefetch next into back buffer
            int nb = buf ^ 1;
#pragma unroll
            for (int r = 0; r < 4; ++r) {
                glds16(ag[r] + kn, &S[wave][nb][r * 16][0]);
                glds16(bg[r] + kn, &S[wave][nb][64 + r * 16][0]);
            }
            // wait ONLY for current buf's 8 loads; prefetch stays in flight
            asm volatile("s_waitcnt vmcnt(8)" ::: "memory");
        } else {
            asm volatile("s_waitcnt vmcnt(0)" ::: "memory");
        }
        short8 av[4], bv[4];
#pragma unroll
        for (int r = 0; r < 4; ++r) {
            av[r] = *(const short8*)(&S[wave][buf][r * 16 + l15][l4 << 3]);
            bv[r] = *(const short8*)(&S[wave][buf][64 + r * 16 + l15][l4 << 3]);
        }
#pragma unroll
        for (int i2 = 0; i2 < 4; ++i2)
#pragma unroll
            for (int j = 0; j < 4; ++j)
                acc[i2][j] = mfma_bf16(av[i2], bv[j], acc[i2][j]);
    }
#pragma unroll
    for (int i2 = 0; i2 < 4; ++i2) {
        int bm = m0 + (i2 << 4) + (l4 << 2);
#pragma unroll
        for (int j = 0; j < 4; ++j) {
            int bn = n0 + (j << 4) + l15;
#pragma unroll
            for (int r = 0; r < 4; ++r)
                epi(acc[i2][j][r], bz, bm + r, bn);
        }
    }
}

// ---------------- gate transpose: gateT[b][h][s] fp32 -> gateNb[b][s][h] bf16 ----------------
__global__ __launch_bounds__(256)
void gate_transpose(const float* __restrict__ gateT, u16* __restrict__ gateNb) {
    __shared__ float tile[32][33];
    int b = blockIdx.z;
    int h0 = blockIdx.x << 5, s0 = blockIdx.y << 5;
    int tx = threadIdx.x & 31, ty = threadIdx.x >> 5;
    const float* gt = gateT + (long)b * HIDH * SS;
    u16* gn = gateNb + (long)b * SS * HIDH;
    for (int r = ty; r < 32; r += 8) {
        int hh = h0 + r, ss = s0 + tx;
        if (hh < HIDH && ss < SS) tile[r][tx] = gt[(long)hh * SS + ss];
    }
    __syncthreads();
    for (int r = ty; r < 32; r += 8) {
        int ss = s0 + r, hh = h0 + tx;
        if (ss < SS && hh < HIDH) gn[(long)ss * HIDH + hh] = f2bu(tile[tx][r]);
    }
}

// ---------------- gate stats: LDS-local hist, few padded atomics ----------------
__global__ __launch_bounds__(256)
void hist_accum_kernel(const float* __restrict__ gateT, int* __restrict__ hist,
                       unsigned* __restrict__ gmaxu) {
    int b = blockIdx.y;
    const float* gb = gateT + (long)b * SS * HIDH;
    __shared__ int lh[129];
    __shared__ float wmx[4];
    for (int i = threadIdx.x; i < 129; i += 256) lh[i] = 0;
    __syncthreads();
    float lmax = -1e30f;
    int base = blockIdx.x * 2048;
#pragma unroll
    for (int e = 0; e < 8; ++e) {
        int idx = base + e * 256 + threadIdx.x;
        if (idx < SS * HIDH) {
            float g = gb[idx];
            lmax = fmaxf(lmax, g);
            float ag = fabsf(g);
            if (ag >= 1.f) {                  // hist[0] never read; >=1 is rare
                int bin = (int)fminf(floorf(ag), 128.f);
                atomicAdd(&lh[bin], 1);
            }
        }
    }
    for (int off = 32; off; off >>= 1) lmax = fmaxf(lmax, __shfl_xor(lmax, off));
    if ((threadIdx.x & 63) == 0) wmx[threadIdx.x >> 6] = lmax;
    __syncthreads();
    if (threadIdx.x == 0) {
        float m = fmaxf(fmaxf(wmx[0], wmx[1]), fmaxf(wmx[2], wmx[3]));
        unsigned bits = __float_as_uint(m);
        unsigned enc = (bits & 0x80000000u) ? ~bits : (bits | 0x80000000u);
        atomicMax(&gmaxu[b * 64], enc);       // own 256B line per batch
    }
    for (int i = threadIdx.x; i < 129; i += 256)
        if (lh[i]) atomicAdd(&hist[b * 256 + i], lh[i]);
}

// counts over gateT[h][s] with integrated per-thread trim
__global__ void counts_kernel(const float* __restrict__ gateT, const int* __restrict__ hist,
                              const unsigned* __restrict__ gmaxu, int* __restrict__ counts) {
    int id = blockIdx.x * 256 + threadIdx.x;
    if (id >= BB * 100 * 120) return;
    int b = id / 12000;
    unsigned enc = gmaxu[b * 64];
    unsigned bits = (enc & 0x80000000u) ? (enc & 0x7FFFFFFFu) : ~enc;
    float gmax = floorf(__uint_as_float(bits));
    int suffix = 0, trim = 1;
    for (int tt = 128; tt >= 1; --tt) {
        suffix += hist[b * 256 + tt];
        if ((float)tt <= gmax && suffix > 90000) { trim = tt; break; }
    }
    float tr = (float)trim;
    int r = id - b * 12000;
    int bi = r / 120, bj = r - bi * 120;
    const float* gb = gateT + (long)b * SS * HIDH;
    int c = 0;
#pragma unroll
    for (int cc = 0; cc < 4; ++cc)
#pragma unroll
        for (int rr = 0; rr < 4; ++rr) {
            float g = gb[(long)(bj * 5 + cc) * SS + bi * 5 + rr];
            c += (fabsf(g) >= tr) ? 1 : 0;
        }
    counts[id] = c;
}

__global__ __launch_bounds__(256)
void t2_kernel(const int* __restrict__ counts, int* __restrict__ t2) {
    int b = blockIdx.x;
    int t = threadIdx.x;
    __shared__ int h2[17];
    __shared__ int smax;
    if (t < 17) h2[t] = 0;
    if (t == 0) smax = 0;
    __syncthreads();
    int lmax = 0;
    for (int i = t; i < 12000; i += 256) {
        int c = counts[b * 12000 + i];
        if (c) atomicAdd(&h2[c], 1);
        lmax = lmax > c ? lmax : c;
    }
    atomicMax(&smax, lmax);
    __syncthreads();
    if (t == 0) {
        int cmax = smax;
        int suffix = 0, best = 0;
        bool found = false;
        for (int tt = 16; tt >= 1; --tt) {
            suffix += h2[tt];
            if (!found && tt <= cmax && suffix > 3600) { best = tt; found = true; }
        }
        t2[b] = found ? best : cmax;
    }
}

extern "C" void kernel_launch(void* const* d_in, const int* in_sizes, int n_in,
                              void* d_out, int out_size, void* d_ws, size_t ws_size,
                              hipStream_t stream) {
    const float* x      = (const float*)d_in[0];
    const float* mask2  = (const float*)d_in[1];
    const float* ln_g   = (const float*)d_in[2];
    const float* ln_b   = (const float*)d_in[3];
    const float* Wh     = (const float*)d_in[4];
    const float* bh     = (const float*)d_in[5];
    const float* Wqk    = (const float*)d_in[6];
    const float* bqk    = (const float*)d_in[7];
    const float* gamma  = (const float*)d_in[8];
    const float* beta   = (const float*)d_in[9];
    const float* rel_emb= (const float*)d_in[10];
    const float* Wout   = (const float*)d_in[11];
    const float* bout   = (const float*)d_in[12];
    float* out = (float*)d_out;
    float* ws  = (float*)d_ws;

    // workspace layout (float offsets; all 16B-aligned)
    float* gateT  = ws;                            //  6,000,000 f
    float* bias   = ws + 6000000;                  //    250,000 f
    u16*   nxb    = (u16*)(ws + 6250000);          // 10000x320 u16
    u16*   WhT    = (u16*)(ws + 7850000);          //  1200x320 u16
    u16*   Wqkb   = (u16*)(ws + 8042000);          //   128x320 u16
    u16*   WoutT  = (u16*)(ws + 8062480);          //   300x608 u16
    u16*   qb     = (u16*)(ws + 8153680);          // 10000x128 u16
    u16*   kb     = (u16*)(ws + 8793680);          // 10000x128 u16
    u16*   attnb  = (u16*)(ws + 9433680);          // 20x500x512 u16
    u16*   vT     = (u16*)(ws + 11993680);         // 20x640x512 u16
    u16*   gatedb = (u16*)(ws + 15270480);         // 10000x608 u16
    u16*   gateNb = (u16*)(ws + 18310480);         // 10000x600 u16
    int*   hist   = (int*)(ws + 21310480);         // 20 x 256-int stride
    unsigned* gmaxu = (unsigned*)(ws + 21315600);  // 20 x 64-uint stride
    int*   counts = (int*)(ws + 21316880);         //   240,000
    int*   t2     = (int*)(ws + 21556880);         //        20

    // 1. prep + LN (1,503,760 items)
    prep_ln_kernel<<<5875, 256, 0, stream>>>(x, ln_g, ln_b, nxb, Wh, Wqk, Wout,
                                             rel_emb, WhT, Wqkb, WoutT, bias,
                                             hist, gmaxu);

    // 2. qk gemm + fused silu/rotary (M=10000, N=128, Kp=320): slice M, 79 m-tiles
    gemm_nb<2><<<80, 256, 0, stream>>>(
        nxb, Wqkb, 320, 320, 320, 0L, 0L, 1, 10, 79,
        EpiQKRot{bqk, gamma, beta, qb, kb});

    // 3. gemm1 transposed -> vT bf16 + gateT fp32 (M=1200, N=10000, Kp=320):
    //    slice N (79 n-tiles -> 8 slices of 10), 10 m-tiles
    gemm_nb<1><<<800, 256, 0, stream>>>(
        WhT, nxb, 320, 320, 320, 0L, 0L, 10, 10, 79, EpiH{bh, vT, gateT});

    // 4. gate transpose -> gateNb bf16
    gate_transpose<<<dim3(19, 16, BB), 256, 0, stream>>>(gateT, gateNb);

    // 5-7. gate statistics (LDS-local hist, padded atomics)
    hist_accum_kernel<<<dim3(147, BB, 1), 256, 0, stream>>>(gateT, hist, gmaxu);
    counts_kernel<<<(BB * 100 * 120 + 255) / 256, 256, 0, stream>>>(gateT, hist, gmaxu, counts);
    t2_kernel<<<BB, 256, 0, stream>>>(counts, t2);

    // 8. scores -> attnb bf16 (per batch 500x500, Kp=128): batch -> XCD, 4x4 tiles
    gemm_nb<0><<<8 * 16 * 3, 256, 0, stream>>>(
        qb, kb, QKD, QKD, QKD,
        (long)SS * QKD, (long)SS * QKD, 4, 4, BB, EpiAttnB{bias, mask2, attnb});

    // 9. attn@v + fused gate mask (per batch 500x640, Kp=512): batch -> XCD, 5x4 tiles
    gemm_nb<0><<<8 * 20 * 3, 256, 0, stream>>>(
        attnb, vT, 512, 512, 512,
        (long)SS * 512, (long)640 * 512, 5, 4, BB, EpiGateN{gateNb, counts, t2, gatedb});

    // 10. out = gated@Wout + bout + x (M=10000, N=300, Kp=608): slice M, 3 n-tiles
    gemm_nb<2><<<240, 256, 0, stream>>>(
        gatedb, WoutT, 608, 608, 608, 0L, 0L, 3, 10, 79, EpiOutB{bout, x, out});
}

// Round 12
// 275.984 us; speedup vs baseline: 1.1858x; 1.1858x over previous
//
#include <hip/hip_runtime.h>
#include <hip/hip_bf16.h>

#define BB 20
#define SS 500
#define DIMD 300
#define HIDH 600
#define QKD 128

typedef unsigned short u16;
typedef __attribute__((ext_vector_type(8))) __bf16 bf16x8;
typedef __attribute__((ext_vector_type(8))) short short8;
typedef __attribute__((ext_vector_type(4))) float floatx4;

__device__ __forceinline__ u16 f2bu(float f) {
    __hip_bfloat16 h = __float2bfloat16(f);
    return *reinterpret_cast<u16*>(&h);
}
__device__ __forceinline__ float bu2f(u16 u) {
    unsigned v = ((unsigned)u) << 16;
    return __uint_as_float(v);
}

__device__ __forceinline__ floatx4 mfma_bf16(short8 a, short8 b, floatx4 c) {
    return __builtin_amdgcn_mfma_f32_16x16x32_bf16(
        __builtin_bit_cast(bf16x8, a), __builtin_bit_cast(bf16x8, b), c, 0, 0, 0);
}

// async global->LDS, 16B/lane; LDS dest = wave-uniform base + lane*16
__device__ __forceinline__ void glds16(const u16* g, u16* l) {
    __builtin_amdgcn_global_load_lds(
        (__attribute__((address_space(1))) const void*)g,
        (__attribute__((address_space(3))) void*)l, 16, 0, 0);
}

// ---------------- merged prep + LayerNorm/shift ----------------
__global__ __launch_bounds__(256)
void prep_ln_kernel(const float* __restrict__ x, const float* __restrict__ lng,
                    const float* __restrict__ lnb, u16* __restrict__ nxb,
                    const float* __restrict__ Wh, const float* __restrict__ Wqk,
                    const float* __restrict__ Wout, const float* __restrict__ rel_emb,
                    u16* __restrict__ WhT, u16* __restrict__ Wqkb,
                    u16* __restrict__ WoutT, float* __restrict__ bias,
                    int* __restrict__ hist, unsigned* __restrict__ gmaxu) {
    long id = (long)blockIdx.x * 256 + threadIdx.x;
    if (id < 640000) {                        // LayerNorm + shift, one wave per row
        int bs = id >> 6;
        int t = id & 63;
        int s = bs % SS;
        const float* xr = x + (long)bs * DIMD;
        float sum = 0.f, sq = 0.f;
        for (int d = t; d < DIMD; d += 64) { float v = xr[d]; sum += v; sq += v * v; }
        for (int off = 1; off < 64; off <<= 1) {
            sum += __shfl_xor(sum, off);
            sq  += __shfl_xor(sq, off);
        }
        float mean = sum * (1.f / DIMD);
        float var  = sq * (1.f / DIMD) - mean * mean;
        float rstd = rsqrtf(var + 1e-5f);
        for (int d = t; d < DIMD; d += 64) {
            float nv = (xr[d] - mean) * rstd * lng[d] + lnb[d];
            if (d < DIMD / 2) {
                if (s < SS - 1) nxb[(long)(bs + 1) * 320 + d] = f2bu(nv);
            } else {
                nxb[(long)bs * 320 + d] = f2bu(nv);
            }
        }
        if (s == 0)
            for (int d = t; d < DIMD / 2; d += 64) nxb[(long)bs * 320 + d] = 0;
        for (int d = DIMD + t; d < 320; d += 64) nxb[(long)bs * 320 + d] = 0;
        return;
    }
    id -= 640000;
    if (id < 384000) {                        // WhT[n][k], k<320
        int k = id / 1200, n = id - (long)k * 1200;
        WhT[(long)n * 320 + k] = (k < 300) ? f2bu(Wh[(long)k * 1200 + n]) : (u16)0;
        return;
    }
    id -= 384000;
    if (id < 40960) {                         // Wqkb[n][k]
        int k = id / 128, n = id - (long)k * 128;
        Wqkb[(long)n * 320 + k] = (k < 300) ? f2bu(Wqk[(long)k * 128 + n]) : (u16)0;
        return;
    }
    id -= 40960;
    if (id < 182400) {                        // WoutT[n][k], k<608
        int k = id / 300, n = id - (long)k * 300;
        WoutT[(long)n * 608 + k] = (k < 600) ? f2bu(Wout[(long)k * 300 + n]) : (u16)0;
        return;
    }
    id -= 182400;
    if (id < 250000) {                        // T5 bias 500x500
        int i = id / 500, j = id - (long)i * 500;
        int n = i - j;
        int ret = (n < 0) ? 16 : 0;
        int na = n < 0 ? -n : n;
        int bucket;
        if (na < 8) bucket = ret + na;
        else {
            int vil = 8 + (int)(logf((float)na * 0.125f) / logf(16.f) * 8.f);
            vil = vil < 15 ? vil : 15;
            bucket = ret + vil;
        }
        bias[id] = rel_emb[bucket] * 11.313708498984761f;
        return;
    }
    id -= 250000;
    if (id < 5120) { hist[id] = 0; return; }   // 20 batches x 256-int stride
    id -= 5120;
    if (id < 1280) gmaxu[id] = 0u;             // 20 batches x 64-uint stride
}

// ---------------- Epilogues ----------------
struct EpiH {            // gemm1 transposed: m = hidden [0,1200), n = token [0,10000)
    const float* bh; u16* vT; float* gateT;
    __device__ void operator()(float acc, int bz, int m, int n) const {
        if (m >= 1200 || n >= 10000) return;
        float v = acc + bh[m];
        v = v / (1.f + expf(-v));
        int b = n / SS, s = n - b * SS;
        if (m < HIDH) vT[((long)b * 640 + m) * 512 + s] = f2bu(v);
        else gateT[((long)b * HIDH + (m - HIDH)) * SS + s] = v;
    }
};
struct EpiQKRot {        // qk + silu + gamma/beta + rotary (NO early return: shuffles)
    const float* bqk; const float* gamma; const float* beta;
    u16* qb; u16* kb;
    __device__ void operator()(float acc, int bz, int m, int n) const {
        float v = acc + bqk[n];
        v = v / (1.f + expf(-v));
        float qp = v * gamma[n] + beta[n];
        float kp = v * gamma[QKD + n] + beta[QKD + n];
        float qx = __shfl_xor(qp, 1);
        float kx = __shfl_xor(kp, 1);
        float qo = qp, ko = kp;
        if (n < 32) {
            int s = m % SS;
            float inv = expf(-(float)(n & ~1) * (logf(10000.f) / 32.f));
            float ang = (float)s * inv;
            float c, sn;
            sincosf(ang, &sn, &c);
            float qr = (n & 1) ? qx : -qx;
            float kr = (n & 1) ? kx : -kx;
            qo = qp * c + qr * sn;
            ko = kp * c + kr * sn;
        }
        if (m < 10000) {
            qb[(long)m * QKD + n] = f2bu(qo);
            kb[(long)m * QKD + n] = f2bu(ko);
        }
    }
};
struct EpiAttnB {        // scores -> (relu((s+bias)/S))^2 * mask -> bf16 [500][512]
    const float* bias; const float* mask; u16* attnb;
    __device__ void operator()(float acc, int b, int m, int n) const {
        if (m >= SS || n >= 512) return;
        float r = 0.f;
        if (n < SS) {
            float s = (acc + bias[m * SS + n]) * (1.f / (float)SS);
            s = fmaxf(s, 0.f);
            r = s * s * mask[m * SS + n];
        }
        attnb[((long)b * SS + m) * 512 + n] = f2bu(r);
    }
};
struct EpiGateN {        // gated = gm * (attn@v) * gate -> bf16 [10000][608]
    const u16* gateNb; const int* counts; const int* t2v; u16* gated;
    __device__ void operator()(float acc, int b, int m, int n) const {
        if (m >= SS || n >= 608) return;
        float r = 0.f;
        if (n < HIDH) {
            float g = bu2f(gateNb[((long)b * SS + m) * HIDH + n]);
            int c = counts[(b * 100 + m / 5) * 120 + n / 5];
            float bv = (c >= t2v[b]) ? 1.f : 0.25f;
            float p = ((m % 5) == 4 || (n % 5) == 4) ? 0.f : 1.f;
            r = acc * g * bv * p;
        }
        gated[((long)(b * SS + m)) * 608 + n] = f2bu(r);
    }
};
struct EpiOutB {         // out = gated@Wout + bout + x
    const float* bout; const float* x; float* out;
    __device__ void operator()(float acc, int b, int m, int n) const {
        if (m >= 10000 || n >= DIMD) return;
        out[(long)m * DIMD + n] = acc + bout[n] + x[(long)m * DIMD + n];
    }
};

// ---------------- barrier-free bf16 MFMA GEMM: per-wave LDS dbuf + XCD pinning ----------------
// C[M,N] = A[M,Kp] * Bt[N,Kp]^T.  R10's proven body: block 64x64 = 4 waves in
// 2x2; each wave owns a 32x32 tile with its OWN private LDS double-buffer.
// No __syncthreads anywhere -> no compiler vmcnt(0) drain; explicit per-wave
// s_waitcnt vmcnt(4) retires only the current buffer's 4 glds while the
// prefetch stays in flight (retirement is issue-ordered, m135).
// 32KB LDS/block -> 5 blocks/CU -> 20 waves/CU of independent latency cover.
// NEW vs R10: 1-D grid with XCD pinning (workgroup->XCD is round-robin on
// linear id).  MODE 0: batch g -> XCD g%8 (scores & attn@v share the pin, so
// attnb stays in one XCD's L2).  MODE 1: slice N into per-XCD groups of TX
// n-tiles.  MODE 2: slice M into groups of TY m-tiles.  Each XCD's working
// set fits its private 4MB L2 (R11 measured FETCH 64.5 -> 7.5 MB).
// Early whole-block return is safe (no barriers).  Staging has NO bounds
// checks: overruns read adjacent ws buffers (finite garbage discarded by
// epilogue guards); K-pads are real zeros in memory.
template<int MODE, class Epi>
__global__ __launch_bounds__(256)
void gemm_nb(const u16* __restrict__ A, const u16* __restrict__ Bt,
             int Kp, int lda, int ldb, long sA, long sB,
             int TX, int TY, int bound, Epi epi) {
    int lin = blockIdx.x;
    int xcd = lin & 7, i = lin >> 3;
    int per = TX * TY;
    int w = i / per;
    int tl = i - w * per;
    int g = xcd + (w << 3);
    int tx = tl % TX, ty = tl / TX;
    int bx, by, bz;
    if (MODE == 0)      { if (g >= bound) return; bx = tx; by = ty; bz = g; }
    else if (MODE == 1) { bx = g * TX + tx; if (bx >= bound) return; by = ty; bz = 0; }
    else                { by = g * TY + ty; if (by >= bound) return; bx = tx; bz = 0; }

    A += (long)bz * sA; Bt += (long)bz * sB;
    int t = threadIdx.x, lane = t & 63, wave = t >> 6;
    int l15 = lane & 15, l4 = lane >> 4;
    int m0 = (by << 6) + ((wave >> 1) << 5);
    int n0 = (bx << 6) + ((wave & 1) << 5);

    // [wave][buf][row 0..31=A,32..63=B][k32] ; unpadded 64B rows (glds contract)
    __shared__ __align__(16) u16 S[4][2][64][32];

    int srow = lane >> 2, scol = (lane & 3) << 3;
    const u16* agp0 = A + (long)(m0 + srow) * lda + scol;
    const u16* agp1 = A + (long)(m0 + 16 + srow) * lda + scol;
    const u16* bgp0 = Bt + (long)(n0 + srow) * ldb + scol;
    const u16* bgp1 = Bt + (long)(n0 + 16 + srow) * ldb + scol;

    floatx4 acc[2][2];
#pragma unroll
    for (int i2 = 0; i2 < 2; ++i2)
#pragma unroll
        for (int j = 0; j < 2; ++j) acc[i2][j] = (floatx4){0.f, 0.f, 0.f, 0.f};

    // prologue stage into buf 0 (4 outstanding)
    glds16(agp0, &S[wave][0][0][0]);
    glds16(agp1, &S[wave][0][16][0]);
    glds16(bgp0, &S[wave][0][32][0]);
    glds16(bgp1, &S[wave][0][48][0]);

    for (int k0 = 0; k0 < Kp; k0 += 32) {
        int buf = (k0 >> 5) & 1;
        int kn = k0 + 32;
        if (kn < Kp) {                       // prefetch next into back buffer
            int nb = buf ^ 1;
            glds16(agp0 + kn, &S[wave][nb][0][0]);
            glds16(agp1 + kn, &S[wave][nb][16][0]);
            glds16(bgp0 + kn, &S[wave][nb][32][0]);
            glds16(bgp1 + kn, &S[wave][nb][48][0]);
            // wait ONLY for current buf's 4 loads; prefetch stays in flight
            asm volatile("s_waitcnt vmcnt(4)" ::: "memory");
        } else {
            asm volatile("s_waitcnt vmcnt(0)" ::: "memory");
        }
        short8 a0 = *(const short8*)(&S[wave][buf][l15][l4 << 3]);
        short8 a1 = *(const short8*)(&S[wave][buf][16 + l15][l4 << 3]);
        short8 b0 = *(const short8*)(&S[wave][buf][32 + l15][l4 << 3]);
        short8 b1 = *(const short8*)(&S[wave][buf][48 + l15][l4 << 3]);
        acc[0][0] = mfma_bf16(a0, b0, acc[0][0]);
        acc[0][1] = mfma_bf16(a0, b1, acc[0][1]);
        acc[1][0] = mfma_bf16(a1, b0, acc[1][0]);
        acc[1][1] = mfma_bf16(a1, b1, acc[1][1]);
    }
#pragma unroll
    for (int i2 = 0; i2 < 2; ++i2) {
        int bm = m0 + (i2 << 4) + (l4 << 2);
#pragma unroll
        for (int j = 0; j < 2; ++j) {
            int bn = n0 + (j << 4) + l15;
#pragma unroll
            for (int r = 0; r < 4; ++r)
                epi(acc[i2][j][r], bz, bm + r, bn);
        }
    }
}

// ---------------- gate transpose: gateT[b][h][s] fp32 -> gateNb[b][s][h] bf16 ----------------
__global__ __launch_bounds__(256)
void gate_transpose(const float* __restrict__ gateT, u16* __restrict__ gateNb) {
    __shared__ float tile[32][33];
    int b = blockIdx.z;
    int h0 = blockIdx.x << 5, s0 = blockIdx.y << 5;
    int tx = threadIdx.x & 31, ty = threadIdx.x >> 5;
    const float* gt = gateT + (long)b * HIDH * SS;
    u16* gn = gateNb + (long)b * SS * HIDH;
    for (int r = ty; r < 32; r += 8) {
        int hh = h0 + r, ss = s0 + tx;
        if (hh < HIDH && ss < SS) tile[r][tx] = gt[(long)hh * SS + ss];
    }
    __syncthreads();
    for (int r = ty; r < 32; r += 8) {
        int ss = s0 + r, hh = h0 + tx;
        if (ss < SS && hh < HIDH) gn[(long)ss * HIDH + hh] = f2bu(tile[tx][r]);
    }
}

// ---------------- gate stats: LDS-local hist, few padded atomics ----------------
__global__ __launch_bounds__(256)
void hist_accum_kernel(const float* __restrict__ gateT, int* __restrict__ hist,
                       unsigned* __restrict__ gmaxu) {
    int b = blockIdx.y;
    const float* gb = gateT + (long)b * SS * HIDH;
    __shared__ int lh[129];
    __shared__ float wmx[4];
    for (int i = threadIdx.x; i < 129; i += 256) lh[i] = 0;
    __syncthreads();
    float lmax = -1e30f;
    int base = blockIdx.x * 2048;
#pragma unroll
    for (int e = 0; e < 8; ++e) {
        int idx = base + e * 256 + threadIdx.x;
        if (idx < SS * HIDH) {
            float g = gb[idx];
            lmax = fmaxf(lmax, g);
            float ag = fabsf(g);
            if (ag >= 1.f) {                  // hist[0] never read; >=1 is rare
                int bin = (int)fminf(floorf(ag), 128.f);
                atomicAdd(&lh[bin], 1);
            }
        }
    }
    for (int off = 32; off; off >>= 1) lmax = fmaxf(lmax, __shfl_xor(lmax, off));
    if ((threadIdx.x & 63) == 0) wmx[threadIdx.x >> 6] = lmax;
    __syncthreads();
    if (threadIdx.x == 0) {
        float m = fmaxf(fmaxf(wmx[0], wmx[1]), fmaxf(wmx[2], wmx[3]));
        unsigned bits = __float_as_uint(m);
        unsigned enc = (bits & 0x80000000u) ? ~bits : (bits | 0x80000000u);
        atomicMax(&gmaxu[b * 64], enc);       // own 256B line per batch
    }
    for (int i = threadIdx.x; i < 129; i += 256)
        if (lh[i]) atomicAdd(&hist[b * 256 + i], lh[i]);
}

// counts over gateT[h][s] with integrated per-thread trim
__global__ void counts_kernel(const float* __restrict__ gateT, const int* __restrict__ hist,
                              const unsigned* __restrict__ gmaxu, int* __restrict__ counts) {
    int id = blockIdx.x * 256 + threadIdx.x;
    if (id >= BB * 100 * 120) return;
    int b = id / 12000;
    unsigned enc = gmaxu[b * 64];
    unsigned bits = (enc & 0x80000000u) ? (enc & 0x7FFFFFFFu) : ~enc;
    float gmax = floorf(__uint_as_float(bits));
    int suffix = 0, trim = 1;
    for (int tt = 128; tt >= 1; --tt) {
        suffix += hist[b * 256 + tt];
        if ((float)tt <= gmax && suffix > 90000) { trim = tt; break; }
    }
    float tr = (float)trim;
    int r = id - b * 12000;
    int bi = r / 120, bj = r - bi * 120;
    const float* gb = gateT + (long)b * SS * HIDH;
    int c = 0;
#pragma unroll
    for (int cc = 0; cc < 4; ++cc)
#pragma unroll
        for (int rr = 0; rr < 4; ++rr) {
            float g = gb[(long)(bj * 5 + cc) * SS + bi * 5 + rr];
            c += (fabsf(g) >= tr) ? 1 : 0;
        }
    counts[id] = c;
}

__global__ __launch_bounds__(256)
void t2_kernel(const int* __restrict__ counts, int* __restrict__ t2) {
    int b = blockIdx.x;
    int t = threadIdx.x;
    __shared__ int h2[17];
    __shared__ int smax;
    if (t < 17) h2[t] = 0;
    if (t == 0) smax = 0;
    __syncthreads();
    int lmax = 0;
    for (int i = t; i < 12000; i += 256) {
        int c = counts[b * 12000 + i];
        if (c) atomicAdd(&h2[c], 1);
        lmax = lmax > c ? lmax : c;
    }
    atomicMax(&smax, lmax);
    __syncthreads();
    if (t == 0) {
        int cmax = smax;
        int suffix = 0, best = 0;
        bool found = false;
        for (int tt = 16; tt >= 1; --tt) {
            suffix += h2[tt];
            if (!found && tt <= cmax && suffix > 3600) { best = tt; found = true; }
        }
        t2[b] = found ? best : cmax;
    }
}

extern "C" void kernel_launch(void* const* d_in, const int* in_sizes, int n_in,
                              void* d_out, int out_size, void* d_ws, size_t ws_size,
                              hipStream_t stream) {
    const float* x      = (const float*)d_in[0];
    const float* mask2  = (const float*)d_in[1];
    const float* ln_g   = (const float*)d_in[2];
    const float* ln_b   = (const float*)d_in[3];
    const float* Wh     = (const float*)d_in[4];
    const float* bh     = (const float*)d_in[5];
    const float* Wqk    = (const float*)d_in[6];
    const float* bqk    = (const float*)d_in[7];
    const float* gamma  = (const float*)d_in[8];
    const float* beta   = (const float*)d_in[9];
    const float* rel_emb= (const float*)d_in[10];
    const float* Wout   = (const float*)d_in[11];
    const float* bout   = (const float*)d_in[12];
    float* out = (float*)d_out;
    float* ws  = (float*)d_ws;

    // workspace layout (float offsets; all 16B-aligned)
    float* gateT  = ws;                            //  6,000,000 f
    float* bias   = ws + 6000000;                  //    250,000 f
    u16*   nxb    = (u16*)(ws + 6250000);          // 10000x320 u16
    u16*   WhT    = (u16*)(ws + 7850000);          //  1200x320 u16
    u16*   Wqkb   = (u16*)(ws + 8042000);          //   128x320 u16
    u16*   WoutT  = (u16*)(ws + 8062480);          //   300x608 u16
    u16*   qb     = (u16*)(ws + 8153680);          // 10000x128 u16
    u16*   kb     = (u16*)(ws + 8793680);          // 10000x128 u16
    u16*   attnb  = (u16*)(ws + 9433680);          // 20x500x512 u16
    u16*   vT     = (u16*)(ws + 11993680);         // 20x640x512 u16
    u16*   gatedb = (u16*)(ws + 15270480);         // 10000x608 u16
    u16*   gateNb = (u16*)(ws + 18310480);         // 10000x600 u16
    int*   hist   = (int*)(ws + 21310480);         // 20 x 256-int stride
    unsigned* gmaxu = (unsigned*)(ws + 21315600);  // 20 x 64-uint stride
    int*   counts = (int*)(ws + 21316880);         //   240,000
    int*   t2     = (int*)(ws + 21556880);         //        20

    // 1. prep + LN (1,503,760 items)
    prep_ln_kernel<<<5875, 256, 0, stream>>>(x, ln_g, ln_b, nxb, Wh, Wqk, Wout,
                                             rel_emb, WhT, Wqkb, WoutT, bias,
                                             hist, gmaxu);

    // 2. qk gemm + fused silu/rotary (M=10000, N=128, Kp=320):
    //    slice M over XCDs (157 m-tiles in 8 groups of 20), TX=2 n-tiles
    gemm_nb<2><<<8 * 2 * 20, 256, 0, stream>>>(
        nxb, Wqkb, 320, 320, 320, 0L, 0L, 2, 20, 157,
        EpiQKRot{bqk, gamma, beta, qb, kb});

    // 3. gemm1 transposed -> vT bf16 + gateT fp32 (M=1200, N=10000, Kp=320):
    //    slice N over XCDs (157 n-tiles in 8 groups of 20), TY=19 m-tiles
    gemm_nb<1><<<8 * 20 * 19, 256, 0, stream>>>(
        WhT, nxb, 320, 320, 320, 0L, 0L, 20, 19, 157, EpiH{bh, vT, gateT});

    // 4. gate transpose -> gateNb bf16
    gate_transpose<<<dim3(19, 16, BB), 256, 0, stream>>>(gateT, gateNb);

    // 5-7. gate statistics (LDS-local hist, padded atomics)
    hist_accum_kernel<<<dim3(147, BB, 1), 256, 0, stream>>>(gateT, hist, gmaxu);
    counts_kernel<<<(BB * 100 * 120 + 255) / 256, 256, 0, stream>>>(gateT, hist, gmaxu, counts);
    t2_kernel<<<BB, 256, 0, stream>>>(counts, t2);

    // 8. scores -> attnb bf16 (per batch 500x500, Kp=128): batch b -> XCD b%8
    gemm_nb<0><<<8 * 8 * 8 * 3, 256, 0, stream>>>(
        qb, kb, QKD, QKD, QKD,
        (long)SS * QKD, (long)SS * QKD, 8, 8, BB, EpiAttnB{bias, mask2, attnb});

    // 9. attn@v + fused gate mask (per batch 500x640, Kp=512): batch b -> XCD b%8
    //    (same pin as scores -> attnb is read from the producing XCD's L2)
    gemm_nb<0><<<8 * 10 * 8 * 3, 256, 0, stream>>>(
        attnb, vT, 512, 512, 512,
        (long)SS * 512, (long)640 * 512, 10, 8, BB, EpiGateN{gateNb, counts, t2, gatedb});

    // 10. out = gated@Wout + bout + x (M=10000, N=300, Kp=608):
    //     slice M over XCDs, TX=5 n-tiles
    gemm_nb<2><<<8 * 5 * 20, 256, 0, stream>>>(
        gatedb, WoutT, 608, 608, 608, 0L, 0L, 5, 20, 157, EpiOutB{bout, x, out});
}